// Round 5
// baseline (728.955 us; speedup 1.0000x reference)
//
#include <hip/hip_runtime.h>
#include <hip/hip_bf16.h>

#define N_NODES 100000
#define N_EDGES 1600000
#define IN_DIM  128
#define HID     64
#define RPW     8          // rows per wave; 4 waves * 8 = 32 rows/block
#define RPB     32         // rows per block
#define UNROLL  16         // edges in flight per wave in aggregate
#define SCAN_ELEMS 1024
#define SCAN_NB   ((N_NODES + SCAN_ELEMS - 1) / SCAN_ELEMS)   // 98

// ---------------------------------------------------------------------------
// h0 = relu(x @ Wi + bi); also emits bf16 copy for the gather table.
// ---------------------------------------------------------------------------
__global__ void gemm_in_kernel(const float* __restrict__ x,
                               const float* __restrict__ Wi,
                               const float* __restrict__ bi,
                               float* __restrict__ h0,
                               __hip_bfloat16* __restrict__ hbf) {
    __shared__ float sW[IN_DIM * HID];   // 32 KB
    __shared__ float sX[RPB * IN_DIM];   // 16 KB
    for (int i = threadIdx.x; i < IN_DIM * HID; i += 256) sW[i] = Wi[i];
    {
        const float4* xb4 = (const float4*)(x + (size_t)blockIdx.x * RPB * IN_DIM);
        float4* sX4 = (float4*)sX;
        #pragma unroll
        for (int i = 0; i < RPB * IN_DIM / 4 / 256; ++i)
            sX4[threadIdx.x + i * 256] = xb4[threadIdx.x + i * 256];
    }
    __syncthreads();

    const int lane = threadIdx.x & 63;
    const int wave = threadIdx.x >> 6;
    const int r0   = wave * RPW;

    float b = bi[lane];
    float acc[RPW];
    #pragma unroll
    for (int r = 0; r < RPW; ++r) acc[r] = b;

    const float4* sX4 = (const float4*)sX;
    for (int k4 = 0; k4 < IN_DIM / 4; ++k4) {
        float4 xv[RPW];
        #pragma unroll
        for (int r = 0; r < RPW; ++r) xv[r] = sX4[(r0 + r) * (IN_DIM / 4) + k4];
        float w0 = sW[(4 * k4 + 0) * HID + lane];
        float w1 = sW[(4 * k4 + 1) * HID + lane];
        float w2 = sW[(4 * k4 + 2) * HID + lane];
        float w3 = sW[(4 * k4 + 3) * HID + lane];
        #pragma unroll
        for (int r = 0; r < RPW; ++r)
            acc[r] += xv[r].x * w0 + xv[r].y * w1 + xv[r].z * w2 + xv[r].w * w3;
    }
    const int row0 = blockIdx.x * RPB + r0;
    #pragma unroll
    for (int r = 0; r < RPW; ++r) {
        float rv = fmaxf(acc[r], 0.0f);
        h0 [(size_t)(row0 + r) * HID + lane] = rv;
        hbf[(size_t)(row0 + r) * HID + lane] = __float2bfloat16(rv);
    }
}

// ---------------------------------------------------------------------------
// hnext = relu(a @ W + b); also emits bf16 copy.
// ---------------------------------------------------------------------------
__global__ void gemm_hid_kernel(const float* __restrict__ a,
                                const float* __restrict__ W,
                                const float* __restrict__ b,
                                float* __restrict__ hnext,
                                __hip_bfloat16* __restrict__ hbf) {
    __shared__ float sW[HID * HID];    // 16 KB
    __shared__ float sX[RPB * HID];    // 8 KB
    for (int i = threadIdx.x; i < HID * HID; i += 256) sW[i] = W[i];
    {
        const float4* ab4 = (const float4*)(a + (size_t)blockIdx.x * RPB * HID);
        float4* sX4 = (float4*)sX;
        #pragma unroll
        for (int i = 0; i < RPB * HID / 4 / 256; ++i)
            sX4[threadIdx.x + i * 256] = ab4[threadIdx.x + i * 256];
    }
    __syncthreads();

    const int lane = threadIdx.x & 63;
    const int wave = threadIdx.x >> 6;
    const int r0   = wave * RPW;

    float bb = b[lane];
    float acc[RPW];
    #pragma unroll
    for (int r = 0; r < RPW; ++r) acc[r] = bb;

    const float4* sX4 = (const float4*)sX;
    for (int k4 = 0; k4 < HID / 4; ++k4) {
        float4 av[RPW];
        #pragma unroll
        for (int r = 0; r < RPW; ++r) av[r] = sX4[(r0 + r) * (HID / 4) + k4];
        float w0 = sW[(4 * k4 + 0) * HID + lane];
        float w1 = sW[(4 * k4 + 1) * HID + lane];
        float w2 = sW[(4 * k4 + 2) * HID + lane];
        float w3 = sW[(4 * k4 + 3) * HID + lane];
        #pragma unroll
        for (int r = 0; r < RPW; ++r)
            acc[r] += av[r].x * w0 + av[r].y * w1 + av[r].z * w2 + av[r].w * w3;
    }
    const int row0 = blockIdx.x * RPB + r0;
    #pragma unroll
    for (int r = 0; r < RPW; ++r) {
        float rv = fmaxf(acc[r], 0.0f);
        hnext[(size_t)(row0 + r) * HID + lane] = rv;
        hbf  [(size_t)(row0 + r) * HID + lane] = __float2bfloat16(rv);
    }
}

// ---------------------------------------------------------------------------
// CSR build
// ---------------------------------------------------------------------------
__global__ void hist_kernel(const int* __restrict__ tgt, int* __restrict__ counts) {
    int e = blockIdx.x * blockDim.x + threadIdx.x;
    if (e < N_EDGES) atomicAdd(&counts[tgt[e]], 1);
}

__global__ void scan_reduce_kernel(const int* __restrict__ counts,
                                   int* __restrict__ blocksums) {
    __shared__ int wtot[4];
    const int tid  = threadIdx.x;
    const int lane = tid & 63;
    const int wid  = tid >> 6;
    const int base = blockIdx.x * SCAN_ELEMS;

    int sum = 0;
    for (int i = tid; i < SCAN_ELEMS; i += 256) {
        int idx = base + i;
        sum += (idx < N_NODES) ? counts[idx] : 0;
    }
    #pragma unroll
    for (int d = 1; d < 64; d <<= 1) sum += __shfl_xor(sum, d);
    if (lane == 0) wtot[wid] = sum;
    __syncthreads();
    if (tid == 0) blocksums[blockIdx.x] = wtot[0] + wtot[1] + wtot[2] + wtot[3];
}

__global__ void scan_base_kernel(const int* __restrict__ blocksums,
                                 int* __restrict__ blockbase) {
    __shared__ int s[128];
    const int tid = threadIdx.x;
    int v = (tid < SCAN_NB) ? blocksums[tid] : 0;
    s[tid] = v;
    __syncthreads();
    for (int off = 1; off < 128; off <<= 1) {
        int t = (tid >= off) ? s[tid - off] : 0;
        __syncthreads();
        s[tid] += t;
        __syncthreads();
    }
    if (tid < SCAN_NB) blockbase[tid] = s[tid] - v;
}

__global__ void scan_write_kernel(const int* __restrict__ counts,
                                  const int* __restrict__ blockbase,
                                  int* __restrict__ offs,
                                  int* __restrict__ cursor) {
    __shared__ int wtot[4];
    const int tid  = threadIdx.x;
    const int lane = tid & 63;
    const int wid  = tid >> 6;
    const int i0   = blockIdx.x * SCAN_ELEMS + tid * 4;

    int4 c;
    if (i0 + 3 < N_NODES) {
        c = *(const int4*)(counts + i0);
    } else {
        c.x = (i0 + 0 < N_NODES) ? counts[i0 + 0] : 0;
        c.y = (i0 + 1 < N_NODES) ? counts[i0 + 1] : 0;
        c.z = (i0 + 2 < N_NODES) ? counts[i0 + 2] : 0;
        c.w = (i0 + 3 < N_NODES) ? counts[i0 + 3] : 0;
    }
    int mysum = c.x + c.y + c.z + c.w;

    int sc = mysum;
    #pragma unroll
    for (int d = 1; d < 64; d <<= 1) {
        int v = __shfl_up(sc, d);
        if (lane >= d) sc += v;
    }
    if (lane == 63) wtot[wid] = sc;
    __syncthreads();
    int wbase = 0;
    for (int w = 0; w < wid; ++w) wbase += wtot[w];

    int o0 = blockbase[blockIdx.x] + wbase + sc - mysum;
    int o1 = o0 + c.x, o2 = o1 + c.y, o3 = o2 + c.z;
    if (i0 + 3 < N_NODES) {
        *(int4*)(offs + i0)   = make_int4(o0, o1, o2, o3);
        *(int4*)(cursor + i0) = make_int4(o0, o1, o2, o3);
    } else {
        if (i0 + 0 < N_NODES) { offs[i0 + 0] = o0; cursor[i0 + 0] = o0; }
        if (i0 + 1 < N_NODES) { offs[i0 + 1] = o1; cursor[i0 + 1] = o1; }
        if (i0 + 2 < N_NODES) { offs[i0 + 2] = o2; cursor[i0 + 2] = o2; }
        if (i0 + 3 < N_NODES) { offs[i0 + 3] = o3; cursor[i0 + 3] = o3; }
    }
}

__global__ void fill_kernel(const int* __restrict__ src,
                            const int* __restrict__ tgt,
                            const float* __restrict__ ea,
                            int* __restrict__ cursor,
                            unsigned long long* __restrict__ pairs) {
    int e = blockIdx.x * blockDim.x + threadIdx.x;
    if (e < N_EDGES) {
        int t   = tgt[e];
        int pos = atomicAdd(&cursor[t], 1);
        unsigned long long v =
            ((unsigned long long)(unsigned int)__float_as_int(ea[e]) << 32) |
            (unsigned int)src[e];
        __builtin_nontemporal_store(v, pairs + pos);  // nt: skip write-allocate
    }
}

// ---------------------------------------------------------------------------
// a[n] = h[n] + sum_e bf16(h)[src_e] * w_e.  One wave per node, lane = column.
// ---------------------------------------------------------------------------
__global__ void aggregate_kernel(const float* __restrict__ h,
                                 const __hip_bfloat16* __restrict__ hbf,
                                 const int* __restrict__ offs,
                                 const int* __restrict__ counts,
                                 const int2* __restrict__ pairs,
                                 float* __restrict__ a) {
    const int lane = threadIdx.x & 63;
    const int node = (blockIdx.x * blockDim.x + threadIdx.x) >> 6;
    if (node >= N_NODES) return;

    const int beg = offs[node];
    const int cnt = counts[node];
    float acc = h[(size_t)node * HID + lane];

    if (cnt > 0) {
        const int last = cnt - 1;
        for (int i = 0; i < cnt; i += UNROLL) {
            int2 p[UNROLL];
            bool live[UNROLL];
            #pragma unroll
            for (int j = 0; j < UNROLL; ++j) {
                int e = i + j;
                live[j] = (e <= last);
                p[j] = pairs[beg + (live[j] ? e : last)];
            }
            float v[UNROLL];
            #pragma unroll
            for (int j = 0; j < UNROLL; ++j)
                v[j] = (float)hbf[(size_t)p[j].x * HID + lane];
            #pragma unroll
            for (int j = 0; j < UNROLL; ++j)
                acc += v[j] * (live[j] ? __int_as_float(p[j].y) : 0.0f);
        }
    }
    a[(size_t)node * HID + lane] = acc;
}

extern "C" void kernel_launch(void* const* d_in, const int* in_sizes, int n_in,
                              void* d_out, int out_size, void* d_ws, size_t ws_size,
                              hipStream_t stream) {
    const float* x   = (const float*)d_in[0];
    const int*   ei  = (const int*)  d_in[1];   // (2, E): [src | tgt]
    const float* ea  = (const float*)d_in[2];
    const float* Wi  = (const float*)d_in[3];
    const float* bi  = (const float*)d_in[4];
    const float* Wl[3] = { (const float*)d_in[5], (const float*)d_in[7], (const float*)d_in[9] };
    const float* bl[3] = { (const float*)d_in[6], (const float*)d_in[8], (const float*)d_in[10] };
    float* out = (float*)d_out;  // (4, N, HID)

    const int* src = ei;
    const int* tgt = ei + N_EDGES;

    // Workspace layout
    float* tmp       = (float*)d_ws;                    // N*HID f32
    int*   counts    = (int*)(tmp + (size_t)N_NODES * HID);
    int*   offs      = counts + N_NODES;
    int*   cursor    = offs   + N_NODES;
    int*   blocksums = cursor + N_NODES;
    int*   blockbase = blocksums + 128;
    unsigned long long* pairs = (unsigned long long*)(blockbase + 128);  // E*8B, 8B-aligned
    __hip_bfloat16* hbf = (__hip_bfloat16*)(pairs + N_EDGES);            // N*HID bf16

    hipMemsetAsync(counts, 0, N_NODES * sizeof(int), stream);

    hist_kernel<<<(N_EDGES + 255) / 256, 256, 0, stream>>>(tgt, counts);
    scan_reduce_kernel<<<SCAN_NB, 256, 0, stream>>>(counts, blocksums);
    scan_base_kernel<<<1, 128, 0, stream>>>(blocksums, blockbase);
    scan_write_kernel<<<SCAN_NB, 256, 0, stream>>>(counts, blockbase, offs, cursor);
    fill_kernel<<<(N_EDGES + 255) / 256, 256, 0, stream>>>(src, tgt, ea, cursor, pairs);

    const int gemm_blocks = N_NODES / RPB;  // 3125
    gemm_in_kernel<<<gemm_blocks, 256, 0, stream>>>(x, Wi, bi, out, hbf);

    for (int l = 0; l < 3; ++l) {
        const float* h = out + (size_t)l * N_NODES * HID;
        float* hn      = out + (size_t)(l + 1) * N_NODES * HID;
        aggregate_kernel<<<(N_NODES + 3) / 4, 256, 0, stream>>>(
            h, hbf, offs, counts, (const int2*)pairs, tmp);
        gemm_hid_kernel<<<gemm_blocks, 256, 0, stream>>>(tmp, Wl[l], bl[l], hn, hbf);
    }
}

// Round 6
// 573.355 us; speedup vs baseline: 1.2714x; 1.2714x over previous
//
#include <hip/hip_runtime.h>
#include <hip/hip_bf16.h>

#define N_NODES 100000
#define N_EDGES 1600000
#define IN_DIM  128
#define HID     64
#define RPW     8          // rows per wave; 4 waves * 8 = 32 rows/block
#define RPB     32         // rows per block
#define UNROLL  8          // edges in flight per wave in aggregate (16 regressed: clamp waste)
#define BIN_NODES 256
#define NBINS   ((N_NODES + BIN_NODES - 1) / BIN_NODES)   // 391
#define EB      2048       // edges per block in bin_hist / bin_scatter

// ---------------------------------------------------------------------------
// h0 = relu(x @ Wi + bi); also emits bf16 copy for the gather table.
// ---------------------------------------------------------------------------
__global__ void gemm_in_kernel(const float* __restrict__ x,
                               const float* __restrict__ Wi,
                               const float* __restrict__ bi,
                               float* __restrict__ h0,
                               __hip_bfloat16* __restrict__ hbf) {
    __shared__ float sW[IN_DIM * HID];   // 32 KB
    __shared__ float sX[RPB * IN_DIM];   // 16 KB
    for (int i = threadIdx.x; i < IN_DIM * HID; i += 256) sW[i] = Wi[i];
    {
        const float4* xb4 = (const float4*)(x + (size_t)blockIdx.x * RPB * IN_DIM);
        float4* sX4 = (float4*)sX;
        #pragma unroll
        for (int i = 0; i < RPB * IN_DIM / 4 / 256; ++i)
            sX4[threadIdx.x + i * 256] = xb4[threadIdx.x + i * 256];
    }
    __syncthreads();

    const int lane = threadIdx.x & 63;
    const int wave = threadIdx.x >> 6;
    const int r0   = wave * RPW;

    float b = bi[lane];
    float acc[RPW];
    #pragma unroll
    for (int r = 0; r < RPW; ++r) acc[r] = b;

    const float4* sX4 = (const float4*)sX;
    for (int k4 = 0; k4 < IN_DIM / 4; ++k4) {
        float4 xv[RPW];
        #pragma unroll
        for (int r = 0; r < RPW; ++r) xv[r] = sX4[(r0 + r) * (IN_DIM / 4) + k4];
        float w0 = sW[(4 * k4 + 0) * HID + lane];
        float w1 = sW[(4 * k4 + 1) * HID + lane];
        float w2 = sW[(4 * k4 + 2) * HID + lane];
        float w3 = sW[(4 * k4 + 3) * HID + lane];
        #pragma unroll
        for (int r = 0; r < RPW; ++r)
            acc[r] += xv[r].x * w0 + xv[r].y * w1 + xv[r].z * w2 + xv[r].w * w3;
    }
    const int row0 = blockIdx.x * RPB + r0;
    #pragma unroll
    for (int r = 0; r < RPW; ++r) {
        float rv = fmaxf(acc[r], 0.0f);
        h0 [(size_t)(row0 + r) * HID + lane] = rv;
        hbf[(size_t)(row0 + r) * HID + lane] = __float2bfloat16(rv);
    }
}

// ---------------------------------------------------------------------------
// hnext = relu(a @ W + b); also emits bf16 copy.
// ---------------------------------------------------------------------------
__global__ void gemm_hid_kernel(const float* __restrict__ a,
                                const float* __restrict__ W,
                                const float* __restrict__ b,
                                float* __restrict__ hnext,
                                __hip_bfloat16* __restrict__ hbf) {
    __shared__ float sW[HID * HID];    // 16 KB
    __shared__ float sX[RPB * HID];    // 8 KB
    for (int i = threadIdx.x; i < HID * HID; i += 256) sW[i] = W[i];
    {
        const float4* ab4 = (const float4*)(a + (size_t)blockIdx.x * RPB * HID);
        float4* sX4 = (float4*)sX;
        #pragma unroll
        for (int i = 0; i < RPB * HID / 4 / 256; ++i)
            sX4[threadIdx.x + i * 256] = ab4[threadIdx.x + i * 256];
    }
    __syncthreads();

    const int lane = threadIdx.x & 63;
    const int wave = threadIdx.x >> 6;
    const int r0   = wave * RPW;

    float bb = b[lane];
    float acc[RPW];
    #pragma unroll
    for (int r = 0; r < RPW; ++r) acc[r] = bb;

    const float4* sX4 = (const float4*)sX;
    for (int k4 = 0; k4 < HID / 4; ++k4) {
        float4 av[RPW];
        #pragma unroll
        for (int r = 0; r < RPW; ++r) av[r] = sX4[(r0 + r) * (HID / 4) + k4];
        float w0 = sW[(4 * k4 + 0) * HID + lane];
        float w1 = sW[(4 * k4 + 1) * HID + lane];
        float w2 = sW[(4 * k4 + 2) * HID + lane];
        float w3 = sW[(4 * k4 + 3) * HID + lane];
        #pragma unroll
        for (int r = 0; r < RPW; ++r)
            acc[r] += av[r].x * w0 + av[r].y * w1 + av[r].z * w2 + av[r].w * w3;
    }
    const int row0 = blockIdx.x * RPB + r0;
    #pragma unroll
    for (int r = 0; r < RPW; ++r) {
        float rv = fmaxf(acc[r], 0.0f);
        hnext[(size_t)(row0 + r) * HID + lane] = rv;
        hbf  [(size_t)(row0 + r) * HID + lane] = __float2bfloat16(rv);
    }
}

// ---------------------------------------------------------------------------
// Binned CSR build.  Record: high32 = w bits, low32 = (local_tgt<<17) | src.
// ---------------------------------------------------------------------------
__global__ void bin_hist_kernel(const int* __restrict__ tgt,
                                int* __restrict__ g_bin_cnt) {
    __shared__ int cnt[NBINS];
    for (int i = threadIdx.x; i < NBINS; i += 256) cnt[i] = 0;
    __syncthreads();
    const int e0 = blockIdx.x * EB;
    for (int i = threadIdx.x; i < EB; i += 256) {
        int e = e0 + i;
        if (e < N_EDGES) atomicAdd(&cnt[tgt[e] >> 8], 1);
    }
    __syncthreads();
    for (int i = threadIdx.x; i < NBINS; i += 256)
        if (cnt[i]) atomicAdd(&g_bin_cnt[i], cnt[i]);
}

__global__ void bin_scan_kernel(const int* __restrict__ g_bin_cnt,
                                int* __restrict__ g_bin_offs,
                                int* __restrict__ g_bin_cursor) {
    __shared__ int s[512];
    const int tid = threadIdx.x;
    int v = (tid < NBINS) ? g_bin_cnt[tid] : 0;
    s[tid] = v;
    __syncthreads();
    for (int off = 1; off < 512; off <<= 1) {
        int t = (tid >= off) ? s[tid - off] : 0;
        __syncthreads();
        s[tid] += t;
        __syncthreads();
    }
    if (tid < NBINS) { g_bin_offs[tid] = s[tid] - v; g_bin_cursor[tid] = s[tid] - v; }
}

__global__ void bin_scatter_kernel(const int* __restrict__ src,
                                   const int* __restrict__ tgt,
                                   const float* __restrict__ ea,
                                   int* __restrict__ g_bin_cursor,
                                   unsigned long long* __restrict__ binned) {
    __shared__ int cnt[NBINS];
    __shared__ int base[NBINS];
    __shared__ int cur[NBINS];
    for (int i = threadIdx.x; i < NBINS; i += 256) cnt[i] = 0;
    __syncthreads();

    const int e0 = blockIdx.x * EB;
    int myb[EB / 256];
    unsigned long long myrec[EB / 256];
    #pragma unroll
    for (int i = 0; i < EB / 256; ++i) {
        int e = e0 + threadIdx.x + i * 256;
        if (e < N_EDGES) {
            int t = tgt[e];
            int b = t >> 8;
            myb[i] = b;
            myrec[i] = ((unsigned long long)(unsigned)__float_as_int(ea[e]) << 32)
                     | ((unsigned)(t & 255) << 17) | (unsigned)src[e];
            atomicAdd(&cnt[b], 1);
        } else {
            myb[i] = -1;
        }
    }
    __syncthreads();
    for (int i = threadIdx.x; i < NBINS; i += 256) {
        cur[i]  = 0;
        base[i] = cnt[i] ? atomicAdd(&g_bin_cursor[i], cnt[i]) : 0;
    }
    __syncthreads();
    #pragma unroll
    for (int i = 0; i < EB / 256; ++i) {
        if (myb[i] >= 0) {
            int r = atomicAdd(&cur[myb[i]], 1);
            binned[base[myb[i]] + r] = myrec[i];
        }
    }
}

// One block per bin: per-node counts+scan in LDS, write offs/counts, scatter
// pairs into this block's private contiguous CSR window (L2-local).
__global__ void fine_fill_kernel(const unsigned long long* __restrict__ binned,
                                 const int* __restrict__ g_bin_offs,
                                 const int* __restrict__ g_bin_cnt,
                                 int* __restrict__ offs,
                                 int* __restrict__ counts,
                                 unsigned long long* __restrict__ pairs) {
    __shared__ int ncnt[256];
    __shared__ int nbase[256];
    __shared__ int wsum[4];
    const int b    = blockIdx.x;
    const int tid  = threadIdx.x;
    const int ebeg = g_bin_offs[b];
    const int ecnt = g_bin_cnt[b];

    ncnt[tid] = 0;
    __syncthreads();
    for (int i = tid; i < ecnt; i += 256) {
        int lt = (int)((binned[ebeg + i] >> 17) & 255);
        atomicAdd(&ncnt[lt], 1);
    }
    __syncthreads();

    // exclusive scan over the 256 per-node counts
    const int lane = tid & 63, wid = tid >> 6;
    int v  = ncnt[tid];
    int sc = v;
    #pragma unroll
    for (int d = 1; d < 64; d <<= 1) {
        int t = __shfl_up(sc, d);
        if (lane >= d) sc += t;
    }
    if (lane == 63) wsum[wid] = sc;
    __syncthreads();
    int wb = 0;
    for (int w = 0; w < wid; ++w) wb += wsum[w];
    int excl = wb + sc - v;
    nbase[tid] = excl;

    const int node = b * BIN_NODES + tid;
    if (node < N_NODES) { offs[node] = ebeg + excl; counts[node] = v; }

    ncnt[tid] = 0;  // reuse as cursor
    __syncthreads();
    for (int i = tid; i < ecnt; i += 256) {
        unsigned long long rec = binned[ebeg + i];
        int lt = (int)((rec >> 17) & 255);
        int r  = atomicAdd(&ncnt[lt], 1);
        pairs[ebeg + nbase[lt] + r] =
            (rec & 0xFFFFFFFF00000000ull) | (rec & 0x1FFFFull);
    }
}

// ---------------------------------------------------------------------------
// a[n] = h[n] + sum_e bf16(h)[src_e] * w_e.  One wave per node, lane = column.
// ---------------------------------------------------------------------------
__global__ void aggregate_kernel(const float* __restrict__ h,
                                 const __hip_bfloat16* __restrict__ hbf,
                                 const int* __restrict__ offs,
                                 const int* __restrict__ counts,
                                 const int2* __restrict__ pairs,
                                 float* __restrict__ a) {
    const int lane = threadIdx.x & 63;
    const int node = (blockIdx.x * blockDim.x + threadIdx.x) >> 6;
    if (node >= N_NODES) return;

    const int beg = offs[node];
    const int cnt = counts[node];
    float acc = h[(size_t)node * HID + lane];

    if (cnt > 0) {
        const int last = cnt - 1;
        for (int i = 0; i < cnt; i += UNROLL) {
            int2 p[UNROLL];
            bool live[UNROLL];
            #pragma unroll
            for (int j = 0; j < UNROLL; ++j) {
                int e = i + j;
                live[j] = (e <= last);
                p[j] = pairs[beg + (live[j] ? e : last)];
            }
            float v[UNROLL];
            #pragma unroll
            for (int j = 0; j < UNROLL; ++j)
                v[j] = (float)hbf[(size_t)p[j].x * HID + lane];
            #pragma unroll
            for (int j = 0; j < UNROLL; ++j)
                acc += v[j] * (live[j] ? __int_as_float(p[j].y) : 0.0f);
        }
    }
    a[(size_t)node * HID + lane] = acc;
}

extern "C" void kernel_launch(void* const* d_in, const int* in_sizes, int n_in,
                              void* d_out, int out_size, void* d_ws, size_t ws_size,
                              hipStream_t stream) {
    const float* x   = (const float*)d_in[0];
    const int*   ei  = (const int*)  d_in[1];   // (2, E): [src | tgt]
    const float* ea  = (const float*)d_in[2];
    const float* Wi  = (const float*)d_in[3];
    const float* bi  = (const float*)d_in[4];
    const float* Wl[3] = { (const float*)d_in[5], (const float*)d_in[7], (const float*)d_in[9] };
    const float* bl[3] = { (const float*)d_in[6], (const float*)d_in[8], (const float*)d_in[10] };
    float* out = (float*)d_out;  // (4, N, HID)

    const int* src = ei;
    const int* tgt = ei + N_EDGES;

    // Workspace layout. binned (CSR-build phase) overlaps tmp (layer phase):
    // binned is dead before the first aggregate writes tmp.
    float* tmp  = (float*)d_ws;                           // N*HID f32 (25.6 MB)
    unsigned long long* binned = (unsigned long long*)d_ws;
    int* offs         = (int*)(tmp + (size_t)N_NODES * HID);
    int* counts       = offs + N_NODES;
    int* g_bin_cnt    = counts + N_NODES;
    int* g_bin_offs   = g_bin_cnt + NBINS;
    int* g_bin_cursor = g_bin_offs + NBINS;
    int* endi         = g_bin_cursor + NBINS;             // 200000+1173 ints (odd)
    unsigned long long* pairs = (unsigned long long*)(endi + 1);   // 8B-aligned
    __hip_bfloat16* hbf = (__hip_bfloat16*)(pairs + N_EDGES);

    hipMemsetAsync(g_bin_cnt, 0, NBINS * sizeof(int), stream);

    const int eb_blocks = (N_EDGES + EB - 1) / EB;  // 782
    bin_hist_kernel   <<<eb_blocks, 256, 0, stream>>>(tgt, g_bin_cnt);
    bin_scan_kernel   <<<1, 512, 0, stream>>>(g_bin_cnt, g_bin_offs, g_bin_cursor);
    bin_scatter_kernel<<<eb_blocks, 256, 0, stream>>>(src, tgt, ea, g_bin_cursor, binned);
    fine_fill_kernel  <<<NBINS, 256, 0, stream>>>(binned, g_bin_offs, g_bin_cnt,
                                                  offs, counts, pairs);

    const int gemm_blocks = N_NODES / RPB;  // 3125
    gemm_in_kernel<<<gemm_blocks, 256, 0, stream>>>(x, Wi, bi, out, hbf);

    for (int l = 0; l < 3; ++l) {
        const float* h = out + (size_t)l * N_NODES * HID;
        float* hn      = out + (size_t)(l + 1) * N_NODES * HID;
        aggregate_kernel<<<(N_NODES + 3) / 4, 256, 0, stream>>>(
            h, hbf, offs, counts, (const int2*)pairs, tmp);
        gemm_hid_kernel<<<gemm_blocks, 256, 0, stream>>>(tmp, Wl[l], bl[l], hn, hbf);
    }
}

// Round 7
// 526.200 us; speedup vs baseline: 1.3853x; 1.0896x over previous
//
#include <hip/hip_runtime.h>
#include <hip/hip_bf16.h>

#define N_NODES 100000
#define N_EDGES 1600000
#define IN_DIM  128
#define HID     64
#define RPW     8          // rows per wave; 4 waves * 8 = 32 rows/block
#define RPB     32         // rows per block
#define BIN_NODES 256
#define NBINS   ((N_NODES + BIN_NODES - 1) / BIN_NODES)   // 391
#define EB      2048       // edges per block in bin_hist / bin_scatter

// ---------------------------------------------------------------------------
// h0 = relu(x @ Wi + bi); also emits bf16 copy for the gather table.
// ---------------------------------------------------------------------------
__global__ void gemm_in_kernel(const float* __restrict__ x,
                               const float* __restrict__ Wi,
                               const float* __restrict__ bi,
                               float* __restrict__ h0,
                               __hip_bfloat16* __restrict__ hbf) {
    __shared__ float sW[IN_DIM * HID];   // 32 KB
    __shared__ float sX[RPB * IN_DIM];   // 16 KB
    for (int i = threadIdx.x; i < IN_DIM * HID; i += 256) sW[i] = Wi[i];
    {
        const float4* xb4 = (const float4*)(x + (size_t)blockIdx.x * RPB * IN_DIM);
        float4* sX4 = (float4*)sX;
        #pragma unroll
        for (int i = 0; i < RPB * IN_DIM / 4 / 256; ++i)
            sX4[threadIdx.x + i * 256] = xb4[threadIdx.x + i * 256];
    }
    __syncthreads();

    const int lane = threadIdx.x & 63;
    const int wave = threadIdx.x >> 6;
    const int r0   = wave * RPW;

    float b = bi[lane];
    float acc[RPW];
    #pragma unroll
    for (int r = 0; r < RPW; ++r) acc[r] = b;

    const float4* sX4 = (const float4*)sX;
    for (int k4 = 0; k4 < IN_DIM / 4; ++k4) {
        float4 xv[RPW];
        #pragma unroll
        for (int r = 0; r < RPW; ++r) xv[r] = sX4[(r0 + r) * (IN_DIM / 4) + k4];
        float w0 = sW[(4 * k4 + 0) * HID + lane];
        float w1 = sW[(4 * k4 + 1) * HID + lane];
        float w2 = sW[(4 * k4 + 2) * HID + lane];
        float w3 = sW[(4 * k4 + 3) * HID + lane];
        #pragma unroll
        for (int r = 0; r < RPW; ++r)
            acc[r] += xv[r].x * w0 + xv[r].y * w1 + xv[r].z * w2 + xv[r].w * w3;
    }
    const int row0 = blockIdx.x * RPB + r0;
    #pragma unroll
    for (int r = 0; r < RPW; ++r) {
        float rv = fmaxf(acc[r], 0.0f);
        h0 [(size_t)(row0 + r) * HID + lane] = rv;
        hbf[(size_t)(row0 + r) * HID + lane] = __float2bfloat16(rv);
    }
}

// ---------------------------------------------------------------------------
// hnext = relu(a @ W + b); also emits bf16 copy.
// ---------------------------------------------------------------------------
__global__ void gemm_hid_kernel(const float* __restrict__ a,
                                const float* __restrict__ W,
                                const float* __restrict__ b,
                                float* __restrict__ hnext,
                                __hip_bfloat16* __restrict__ hbf) {
    __shared__ float sW[HID * HID];    // 16 KB
    __shared__ float sX[RPB * HID];    // 8 KB
    for (int i = threadIdx.x; i < HID * HID; i += 256) sW[i] = W[i];
    {
        const float4* ab4 = (const float4*)(a + (size_t)blockIdx.x * RPB * HID);
        float4* sX4 = (float4*)sX;
        #pragma unroll
        for (int i = 0; i < RPB * HID / 4 / 256; ++i)
            sX4[threadIdx.x + i * 256] = ab4[threadIdx.x + i * 256];
    }
    __syncthreads();

    const int lane = threadIdx.x & 63;
    const int wave = threadIdx.x >> 6;
    const int r0   = wave * RPW;

    float bb = b[lane];
    float acc[RPW];
    #pragma unroll
    for (int r = 0; r < RPW; ++r) acc[r] = bb;

    const float4* sX4 = (const float4*)sX;
    for (int k4 = 0; k4 < HID / 4; ++k4) {
        float4 av[RPW];
        #pragma unroll
        for (int r = 0; r < RPW; ++r) av[r] = sX4[(r0 + r) * (HID / 4) + k4];
        float w0 = sW[(4 * k4 + 0) * HID + lane];
        float w1 = sW[(4 * k4 + 1) * HID + lane];
        float w2 = sW[(4 * k4 + 2) * HID + lane];
        float w3 = sW[(4 * k4 + 3) * HID + lane];
        #pragma unroll
        for (int r = 0; r < RPW; ++r)
            acc[r] += av[r].x * w0 + av[r].y * w1 + av[r].z * w2 + av[r].w * w3;
    }
    const int row0 = blockIdx.x * RPB + r0;
    #pragma unroll
    for (int r = 0; r < RPW; ++r) {
        float rv = fmaxf(acc[r], 0.0f);
        hnext[(size_t)(row0 + r) * HID + lane] = rv;
        hbf  [(size_t)(row0 + r) * HID + lane] = __float2bfloat16(rv);
    }
}

// ---------------------------------------------------------------------------
// Binned CSR build.  Record: high32 = w bits, low32 = (local_tgt<<17) | src.
// ---------------------------------------------------------------------------
__global__ void bin_hist_kernel(const int* __restrict__ tgt,
                                int* __restrict__ g_bin_cnt) {
    __shared__ int cnt[NBINS];
    for (int i = threadIdx.x; i < NBINS; i += 256) cnt[i] = 0;
    __syncthreads();
    const int e0 = blockIdx.x * EB;
    for (int i = threadIdx.x; i < EB; i += 256) {
        int e = e0 + i;
        if (e < N_EDGES) atomicAdd(&cnt[tgt[e] >> 8], 1);
    }
    __syncthreads();
    for (int i = threadIdx.x; i < NBINS; i += 256)
        if (cnt[i]) atomicAdd(&g_bin_cnt[i], cnt[i]);
}

__global__ void bin_scan_kernel(const int* __restrict__ g_bin_cnt,
                                int* __restrict__ g_bin_offs,
                                int* __restrict__ g_bin_cursor) {
    __shared__ int s[512];
    const int tid = threadIdx.x;
    int v = (tid < NBINS) ? g_bin_cnt[tid] : 0;
    s[tid] = v;
    __syncthreads();
    for (int off = 1; off < 512; off <<= 1) {
        int t = (tid >= off) ? s[tid - off] : 0;
        __syncthreads();
        s[tid] += t;
        __syncthreads();
    }
    if (tid < NBINS) { g_bin_offs[tid] = s[tid] - v; g_bin_cursor[tid] = s[tid] - v; }
}

__global__ void bin_scatter_kernel(const int* __restrict__ src,
                                   const int* __restrict__ tgt,
                                   const float* __restrict__ ea,
                                   int* __restrict__ g_bin_cursor,
                                   unsigned long long* __restrict__ binned) {
    __shared__ int cnt[NBINS];
    __shared__ int base[NBINS];
    __shared__ int cur[NBINS];
    for (int i = threadIdx.x; i < NBINS; i += 256) cnt[i] = 0;
    __syncthreads();

    const int e0 = blockIdx.x * EB;
    int myb[EB / 256];
    unsigned long long myrec[EB / 256];
    #pragma unroll
    for (int i = 0; i < EB / 256; ++i) {
        int e = e0 + threadIdx.x + i * 256;
        if (e < N_EDGES) {
            int t = tgt[e];
            int b = t >> 8;
            myb[i] = b;
            myrec[i] = ((unsigned long long)(unsigned)__float_as_int(ea[e]) << 32)
                     | ((unsigned)(t & 255) << 17) | (unsigned)src[e];
            atomicAdd(&cnt[b], 1);
        } else {
            myb[i] = -1;
        }
    }
    __syncthreads();
    for (int i = threadIdx.x; i < NBINS; i += 256) {
        cur[i]  = 0;
        base[i] = cnt[i] ? atomicAdd(&g_bin_cursor[i], cnt[i]) : 0;
    }
    __syncthreads();
    #pragma unroll
    for (int i = 0; i < EB / 256; ++i) {
        if (myb[i] >= 0) {
            int r = atomicAdd(&cur[myb[i]], 1);
            binned[base[myb[i]] + r] = myrec[i];
        }
    }
}

__global__ void fine_fill_kernel(const unsigned long long* __restrict__ binned,
                                 const int* __restrict__ g_bin_offs,
                                 const int* __restrict__ g_bin_cnt,
                                 int* __restrict__ offs,
                                 int* __restrict__ counts,
                                 unsigned long long* __restrict__ pairs) {
    __shared__ int ncnt[256];
    __shared__ int nbase[256];
    __shared__ int wsum[4];
    const int b    = blockIdx.x;
    const int tid  = threadIdx.x;
    const int ebeg = g_bin_offs[b];
    const int ecnt = g_bin_cnt[b];

    ncnt[tid] = 0;
    __syncthreads();
    for (int i = tid; i < ecnt; i += 256) {
        int lt = (int)((binned[ebeg + i] >> 17) & 255);
        atomicAdd(&ncnt[lt], 1);
    }
    __syncthreads();

    const int lane = tid & 63, wid = tid >> 6;
    int v  = ncnt[tid];
    int sc = v;
    #pragma unroll
    for (int d = 1; d < 64; d <<= 1) {
        int t = __shfl_up(sc, d);
        if (lane >= d) sc += t;
    }
    if (lane == 63) wsum[wid] = sc;
    __syncthreads();
    int wb = 0;
    for (int w = 0; w < wid; ++w) wb += wsum[w];
    int excl = wb + sc - v;
    nbase[tid] = excl;

    const int node = b * BIN_NODES + tid;
    if (node < N_NODES) { offs[node] = ebeg + excl; counts[node] = v; }

    ncnt[tid] = 0;  // reuse as cursor
    __syncthreads();
    for (int i = tid; i < ecnt; i += 256) {
        unsigned long long rec = binned[ebeg + i];
        int lt = (int)((rec >> 17) & 255);
        int r  = atomicAdd(&ncnt[lt], 1);
        pairs[ebeg + nbase[lt] + r] =
            (rec & 0xFFFFFFFF00000000ull) | (rec & 0x1FFFFull);
    }
}

// ---------------------------------------------------------------------------
// a[n] = h[n] + sum_e bf16(h)[src_e] * w_e.
// Wave = 4 groups x 16 lanes. Group g handles edge i+g; each lane holds 4
// cols (8 B gather). One gather instruction serves 4 edges (512 B).
// Cross-group shfl_xor reduction at the end.
// ---------------------------------------------------------------------------
__global__ void aggregate_kernel(const float* __restrict__ h,
                                 const __hip_bfloat16* __restrict__ hbf,
                                 const int* __restrict__ offs,
                                 const int* __restrict__ counts,
                                 const int2* __restrict__ pairs,
                                 float* __restrict__ a) {
    const int lane = threadIdx.x & 63;
    const int node = (blockIdx.x * blockDim.x + threadIdx.x) >> 6;
    if (node >= N_NODES) return;

    const int grp = lane >> 4;      // 0..3
    const int sub = lane & 15;      // col quad: cols sub*4 .. sub*4+3

    const int beg = offs[node];
    const int cnt = counts[node];

    float ax = 0.f, ay = 0.f, az = 0.f, aw = 0.f;

    if (cnt > 0) {
        const int last = cnt - 1;
        for (int i = 0; i < cnt; i += 8) {
            int e0 = i + grp;
            int e1 = i + 4 + grp;
            bool l0 = (e0 <= last);
            bool l1 = (e1 <= last);
            int2 p0 = pairs[beg + (l0 ? e0 : last)];
            int2 p1 = pairs[beg + (l1 ? e1 : last)];
            uint2 g0 = *(const uint2*)(hbf + (size_t)p0.x * HID + sub * 4);
            uint2 g1 = *(const uint2*)(hbf + (size_t)p1.x * HID + sub * 4);
            float w0 = l0 ? __int_as_float(p0.y) : 0.0f;
            float w1 = l1 ? __int_as_float(p1.y) : 0.0f;
            ax += w0 * __uint_as_float(g0.x << 16);
            ay += w0 * __uint_as_float(g0.x & 0xFFFF0000u);
            az += w0 * __uint_as_float(g0.y << 16);
            aw += w0 * __uint_as_float(g0.y & 0xFFFF0000u);
            ax += w1 * __uint_as_float(g1.x << 16);
            ay += w1 * __uint_as_float(g1.x & 0xFFFF0000u);
            az += w1 * __uint_as_float(g1.y << 16);
            aw += w1 * __uint_as_float(g1.y & 0xFFFF0000u);
        }
    }

    // reduce across the 4 groups (lanes differing in bits 4,5)
    ax += __shfl_xor(ax, 16); ay += __shfl_xor(ay, 16);
    az += __shfl_xor(az, 16); aw += __shfl_xor(aw, 16);
    ax += __shfl_xor(ax, 32); ay += __shfl_xor(ay, 32);
    az += __shfl_xor(az, 32); aw += __shfl_xor(aw, 32);

    if (grp == 0) {
        const float4 hv = *(const float4*)(h + (size_t)node * HID + sub * 4);
        float4 o;
        o.x = hv.x + ax; o.y = hv.y + ay; o.z = hv.z + az; o.w = hv.w + aw;
        *(float4*)(a + (size_t)node * HID + sub * 4) = o;
    }
}

extern "C" void kernel_launch(void* const* d_in, const int* in_sizes, int n_in,
                              void* d_out, int out_size, void* d_ws, size_t ws_size,
                              hipStream_t stream) {
    const float* x   = (const float*)d_in[0];
    const int*   ei  = (const int*)  d_in[1];   // (2, E): [src | tgt]
    const float* ea  = (const float*)d_in[2];
    const float* Wi  = (const float*)d_in[3];
    const float* bi  = (const float*)d_in[4];
    const float* Wl[3] = { (const float*)d_in[5], (const float*)d_in[7], (const float*)d_in[9] };
    const float* bl[3] = { (const float*)d_in[6], (const float*)d_in[8], (const float*)d_in[10] };
    float* out = (float*)d_out;  // (4, N, HID)

    const int* src = ei;
    const int* tgt = ei + N_EDGES;

    // Workspace layout. binned (CSR-build phase) overlaps tmp (layer phase).
    float* tmp  = (float*)d_ws;                           // N*HID f32 (25.6 MB)
    unsigned long long* binned = (unsigned long long*)d_ws;
    int* offs         = (int*)(tmp + (size_t)N_NODES * HID);
    int* counts       = offs + N_NODES;
    int* g_bin_cnt    = counts + N_NODES;
    int* g_bin_offs   = g_bin_cnt + NBINS;
    int* g_bin_cursor = g_bin_offs + NBINS;
    int* endi         = g_bin_cursor + NBINS;
    unsigned long long* pairs = (unsigned long long*)(endi + 1);   // 8B-aligned
    __hip_bfloat16* hbf = (__hip_bfloat16*)(pairs + N_EDGES);

    hipMemsetAsync(g_bin_cnt, 0, NBINS * sizeof(int), stream);

    const int eb_blocks = (N_EDGES + EB - 1) / EB;  // 782
    bin_hist_kernel   <<<eb_blocks, 256, 0, stream>>>(tgt, g_bin_cnt);
    bin_scan_kernel   <<<1, 512, 0, stream>>>(g_bin_cnt, g_bin_offs, g_bin_cursor);
    bin_scatter_kernel<<<eb_blocks, 256, 0, stream>>>(src, tgt, ea, g_bin_cursor, binned);
    fine_fill_kernel  <<<NBINS, 256, 0, stream>>>(binned, g_bin_offs, g_bin_cnt,
                                                  offs, counts, pairs);

    const int gemm_blocks = N_NODES / RPB;  // 3125
    gemm_in_kernel<<<gemm_blocks, 256, 0, stream>>>(x, Wi, bi, out, hbf);

    for (int l = 0; l < 3; ++l) {
        const float* h = out + (size_t)l * N_NODES * HID;
        float* hn      = out + (size_t)(l + 1) * N_NODES * HID;
        aggregate_kernel<<<(N_NODES + 3) / 4, 256, 0, stream>>>(
            h, hbf, offs, counts, (const int2*)pairs, tmp);
        gemm_hid_kernel<<<gemm_blocks, 256, 0, stream>>>(tmp, Wl[l], bl[l], hn, hbf);
    }
}

// Round 8
// 489.296 us; speedup vs baseline: 1.4898x; 1.0754x over previous
//
#include <hip/hip_runtime.h>
#include <hip/hip_bf16.h>

#define N_NODES 100000
#define N_EDGES 1600000
#define IN_DIM  128
#define HID     64
#define BIN_NODES 256
#define NBINS   ((N_NODES + BIN_NODES - 1) / BIN_NODES)   // 391
#define EB      2048       // edges per block in bin_hist / bin_scatter

#define PITCH_IN  152      // bf16 units per LDS row for K=128 (+24 pad: 2-way banks, 16B-aligned)
#define PITCH_HID 88       // bf16 units per LDS row for K=64  (+24 pad)

typedef __attribute__((ext_vector_type(8))) short bf16x8;   // MFMA A/B frag (4 VGPRs)
typedef __attribute__((ext_vector_type(4))) float f32x4;    // MFMA C/D frag

__device__ inline unsigned short f2bf(float f) {
    __hip_bfloat16 b = __float2bfloat16(f);
    return *reinterpret_cast<unsigned short*>(&b);
}

// ---------------------------------------------------------------------------
// Pre-pack W matrices into B-fragment order bf16:
// flat = (((kc*4 + nt)*4 + quad)*16 + n16)*8 + j ;  k = kc*32+quad*8+j, n = nt*16+n16
// ---------------------------------------------------------------------------
__global__ void wf_prep_kernel(const float* __restrict__ Wi,
                               const float* __restrict__ W1,
                               const float* __restrict__ W2,
                               const float* __restrict__ W3,
                               unsigned short* __restrict__ wf_in,
                               unsigned short* __restrict__ wf_hid) {
    int t = blockIdx.x * 256 + threadIdx.x;
    if (t < 8192) {  // Wi: K=128 -> kc in 0..3
        int j = t & 7, n16 = (t >> 3) & 15, quad = (t >> 7) & 3, nt = (t >> 9) & 3, kc = t >> 11;
        int k = kc * 32 + quad * 8 + j, n = nt * 16 + n16;
        wf_in[t] = f2bf(Wi[k * HID + n]);
    }
    if (t < 4096) {  // W1..W3: K=64 -> kc in 0..1
        int j = t & 7, n16 = (t >> 3) & 15, quad = (t >> 7) & 3, nt = (t >> 9) & 3, kc = t >> 11;
        int k = kc * 32 + quad * 8 + j, n = nt * 16 + n16;
        wf_hid[t]        = f2bf(W1[k * HID + n]);
        wf_hid[4096 + t] = f2bf(W2[k * HID + n]);
        wf_hid[8192 + t] = f2bf(W3[k * HID + n]);
    }
}

// ---------------------------------------------------------------------------
// h0 = relu(x @ Wi + bi) via bf16 MFMA. Block = 64 rows, wave = 16 rows.
// ---------------------------------------------------------------------------
__global__ __launch_bounds__(256) void gemm_in_kernel(
        const float* __restrict__ x,
        const unsigned short* __restrict__ wf,   // fragment-order Wi (bf16 bits)
        const float* __restrict__ bi,
        float* __restrict__ h0,
        __hip_bfloat16* __restrict__ hbf) {
    __shared__ unsigned short sX[64 * PITCH_IN];   // 19456 B
    const int tid  = threadIdx.x;
    const int row0 = blockIdx.x * 64;

    // Stage x tile (64 x 128 f32 -> bf16), coalesced float4 reads, 8B LDS writes.
    #pragma unroll
    for (int it = 0; it < 8; ++it) {
        int i  = tid + it * 256;
        int r  = i >> 5;        // 32 float4 per row
        int kq = i & 31;
        int rg = row0 + r;
        float4 v = (rg < N_NODES)
                 ? ((const float4*)x)[(size_t)rg * (IN_DIM / 4) + kq]
                 : make_float4(0.f, 0.f, 0.f, 0.f);
        ushort4 pk;
        pk.x = f2bf(v.x); pk.y = f2bf(v.y); pk.z = f2bf(v.z); pk.w = f2bf(v.w);
        *(ushort4*)(sX + r * PITCH_IN + kq * 4) = pk;
    }
    __syncthreads();

    const int lane = tid & 63;
    const int wid  = tid >> 6;
    const int l16  = lane & 15;
    const int q    = lane >> 4;

    f32x4 acc[4] = {{0,0,0,0},{0,0,0,0},{0,0,0,0},{0,0,0,0}};
    const bf16x8* wf8 = (const bf16x8*)wf;

    #pragma unroll
    for (int kc = 0; kc < 4; ++kc) {
        bf16x8 af = *(const bf16x8*)(sX + (wid * 16 + l16) * PITCH_IN + kc * 32 + q * 8);
        #pragma unroll
        for (int nt = 0; nt < 4; ++nt) {
            bf16x8 bfr = wf8[((kc * 4 + nt) * 4 + q) * 16 + l16];
            acc[nt] = __builtin_amdgcn_mfma_f32_16x16x32_bf16(af, bfr, acc[nt], 0, 0, 0);
        }
    }

    // Epilogue: C/D layout col = lane&15, row = quad*4 + reg  [m89]
    #pragma unroll
    for (int nt = 0; nt < 4; ++nt) {
        float bb = bi[nt * 16 + l16];
        #pragma unroll
        for (int reg = 0; reg < 4; ++reg) {
            int rg = row0 + wid * 16 + q * 4 + reg;
            if (rg < N_NODES) {
                float v = fmaxf(acc[nt][reg] + bb, 0.0f);
                h0 [(size_t)rg * HID + nt * 16 + l16] = v;
                hbf[(size_t)rg * HID + nt * 16 + l16] = __float2bfloat16(v);
            }
        }
    }
}

// ---------------------------------------------------------------------------
// hnext = relu(a @ W + b) via bf16 MFMA (K=64), same structure.
// ---------------------------------------------------------------------------
__global__ __launch_bounds__(256) void gemm_hid_kernel(
        const float* __restrict__ a,
        const unsigned short* __restrict__ wf,   // fragment-order W (bf16 bits)
        const float* __restrict__ b,
        float* __restrict__ hnext,
        __hip_bfloat16* __restrict__ hbf) {
    __shared__ unsigned short sX[64 * PITCH_HID];  // 11264 B
    const int tid  = threadIdx.x;
    const int row0 = blockIdx.x * 64;

    #pragma unroll
    for (int it = 0; it < 4; ++it) {
        int i  = tid + it * 256;
        int r  = i >> 4;        // 16 float4 per row
        int kq = i & 15;
        int rg = row0 + r;
        float4 v = (rg < N_NODES)
                 ? ((const float4*)a)[(size_t)rg * (HID / 4) + kq]
                 : make_float4(0.f, 0.f, 0.f, 0.f);
        ushort4 pk;
        pk.x = f2bf(v.x); pk.y = f2bf(v.y); pk.z = f2bf(v.z); pk.w = f2bf(v.w);
        *(ushort4*)(sX + r * PITCH_HID + kq * 4) = pk;
    }
    __syncthreads();

    const int lane = tid & 63;
    const int wid  = tid >> 6;
    const int l16  = lane & 15;
    const int q    = lane >> 4;

    f32x4 acc[4] = {{0,0,0,0},{0,0,0,0},{0,0,0,0},{0,0,0,0}};
    const bf16x8* wf8 = (const bf16x8*)wf;

    #pragma unroll
    for (int kc = 0; kc < 2; ++kc) {
        bf16x8 af = *(const bf16x8*)(sX + (wid * 16 + l16) * PITCH_HID + kc * 32 + q * 8);
        #pragma unroll
        for (int nt = 0; nt < 4; ++nt) {
            bf16x8 bfr = wf8[((kc * 4 + nt) * 4 + q) * 16 + l16];
            acc[nt] = __builtin_amdgcn_mfma_f32_16x16x32_bf16(af, bfr, acc[nt], 0, 0, 0);
        }
    }

    #pragma unroll
    for (int nt = 0; nt < 4; ++nt) {
        float bb = b[nt * 16 + l16];
        #pragma unroll
        for (int reg = 0; reg < 4; ++reg) {
            int rg = row0 + wid * 16 + q * 4 + reg;
            if (rg < N_NODES) {
                float v = fmaxf(acc[nt][reg] + bb, 0.0f);
                hnext[(size_t)rg * HID + nt * 16 + l16] = v;
                hbf  [(size_t)rg * HID + nt * 16 + l16] = __float2bfloat16(v);
            }
        }
    }
}

// ---------------------------------------------------------------------------
// Binned CSR build.  Record: high32 = w bits, low32 = (local_tgt<<17) | src.
// ---------------------------------------------------------------------------
__global__ void bin_hist_kernel(const int* __restrict__ tgt,
                                int* __restrict__ g_bin_cnt) {
    __shared__ int cnt[NBINS];
    for (int i = threadIdx.x; i < NBINS; i += 256) cnt[i] = 0;
    __syncthreads();
    const int e0 = blockIdx.x * EB;
    for (int i = threadIdx.x; i < EB; i += 256) {
        int e = e0 + i;
        if (e < N_EDGES) atomicAdd(&cnt[tgt[e] >> 8], 1);
    }
    __syncthreads();
    for (int i = threadIdx.x; i < NBINS; i += 256)
        if (cnt[i]) atomicAdd(&g_bin_cnt[i], cnt[i]);
}

__global__ void bin_scan_kernel(const int* __restrict__ g_bin_cnt,
                                int* __restrict__ g_bin_offs,
                                int* __restrict__ g_bin_cursor) {
    __shared__ int s[512];
    const int tid = threadIdx.x;
    int v = (tid < NBINS) ? g_bin_cnt[tid] : 0;
    s[tid] = v;
    __syncthreads();
    for (int off = 1; off < 512; off <<= 1) {
        int t = (tid >= off) ? s[tid - off] : 0;
        __syncthreads();
        s[tid] += t;
        __syncthreads();
    }
    if (tid < NBINS) { g_bin_offs[tid] = s[tid] - v; g_bin_cursor[tid] = s[tid] - v; }
}

__global__ void bin_scatter_kernel(const int* __restrict__ src,
                                   const int* __restrict__ tgt,
                                   const float* __restrict__ ea,
                                   int* __restrict__ g_bin_cursor,
                                   unsigned long long* __restrict__ binned) {
    __shared__ int cnt[NBINS];
    __shared__ int base[NBINS];
    __shared__ int cur[NBINS];
    for (int i = threadIdx.x; i < NBINS; i += 256) cnt[i] = 0;
    __syncthreads();

    const int e0 = blockIdx.x * EB;
    int myb[EB / 256];
    unsigned long long myrec[EB / 256];
    #pragma unroll
    for (int i = 0; i < EB / 256; ++i) {
        int e = e0 + threadIdx.x + i * 256;
        if (e < N_EDGES) {
            int t = tgt[e];
            int b = t >> 8;
            myb[i] = b;
            myrec[i] = ((unsigned long long)(unsigned)__float_as_int(ea[e]) << 32)
                     | ((unsigned)(t & 255) << 17) | (unsigned)src[e];
            atomicAdd(&cnt[b], 1);
        } else {
            myb[i] = -1;
        }
    }
    __syncthreads();
    for (int i = threadIdx.x; i < NBINS; i += 256) {
        cur[i]  = 0;
        base[i] = cnt[i] ? atomicAdd(&g_bin_cursor[i], cnt[i]) : 0;
    }
    __syncthreads();
    #pragma unroll
    for (int i = 0; i < EB / 256; ++i) {
        if (myb[i] >= 0) {
            int r = atomicAdd(&cur[myb[i]], 1);
            binned[base[myb[i]] + r] = myrec[i];
        }
    }
}

__global__ void fine_fill_kernel(const unsigned long long* __restrict__ binned,
                                 const int* __restrict__ g_bin_offs,
                                 const int* __restrict__ g_bin_cnt,
                                 int* __restrict__ offs,
                                 int* __restrict__ counts,
                                 unsigned long long* __restrict__ pairs) {
    __shared__ int ncnt[256];
    __shared__ int nbase[256];
    __shared__ int wsum[4];
    const int b    = blockIdx.x;
    const int tid  = threadIdx.x;
    const int ebeg = g_bin_offs[b];
    const int ecnt = g_bin_cnt[b];

    ncnt[tid] = 0;
    __syncthreads();
    for (int i = tid; i < ecnt; i += 256) {
        int lt = (int)((binned[ebeg + i] >> 17) & 255);
        atomicAdd(&ncnt[lt], 1);
    }
    __syncthreads();

    const int lane = tid & 63, wid = tid >> 6;
    int v  = ncnt[tid];
    int sc = v;
    #pragma unroll
    for (int d = 1; d < 64; d <<= 1) {
        int t = __shfl_up(sc, d);
        if (lane >= d) sc += t;
    }
    if (lane == 63) wsum[wid] = sc;
    __syncthreads();
    int wb = 0;
    for (int w = 0; w < wid; ++w) wb += wsum[w];
    int excl = wb + sc - v;
    nbase[tid] = excl;

    const int node = b * BIN_NODES + tid;
    if (node < N_NODES) { offs[node] = ebeg + excl; counts[node] = v; }

    ncnt[tid] = 0;  // reuse as cursor
    __syncthreads();
    for (int i = tid; i < ecnt; i += 256) {
        unsigned long long rec = binned[ebeg + i];
        int lt = (int)((rec >> 17) & 255);
        int r  = atomicAdd(&ncnt[lt], 1);
        pairs[ebeg + nbase[lt] + r] =
            (rec & 0xFFFFFFFF00000000ull) | (rec & 0x1FFFFull);
    }
}

// ---------------------------------------------------------------------------
// a[n] = h[n] + sum_e bf16(h)[src_e] * w_e.
// Wave = 4 groups x 16 lanes; group g handles edge i+g; lane loads 4 cols (8B).
// ---------------------------------------------------------------------------
__global__ void aggregate_kernel(const float* __restrict__ h,
                                 const __hip_bfloat16* __restrict__ hbf,
                                 const int* __restrict__ offs,
                                 const int* __restrict__ counts,
                                 const int2* __restrict__ pairs,
                                 float* __restrict__ a) {
    const int lane = threadIdx.x & 63;
    const int node = (blockIdx.x * blockDim.x + threadIdx.x) >> 6;
    if (node >= N_NODES) return;

    const int grp = lane >> 4;
    const int sub = lane & 15;

    const int beg = offs[node];
    const int cnt = counts[node];

    float ax = 0.f, ay = 0.f, az = 0.f, aw = 0.f;

    if (cnt > 0) {
        const int last = cnt - 1;
        for (int i = 0; i < cnt; i += 8) {
            int e0 = i + grp;
            int e1 = i + 4 + grp;
            bool l0 = (e0 <= last);
            bool l1 = (e1 <= last);
            int2 p0 = pairs[beg + (l0 ? e0 : last)];
            int2 p1 = pairs[beg + (l1 ? e1 : last)];
            uint2 g0 = *(const uint2*)(hbf + (size_t)p0.x * HID + sub * 4);
            uint2 g1 = *(const uint2*)(hbf + (size_t)p1.x * HID + sub * 4);
            float w0 = l0 ? __int_as_float(p0.y) : 0.0f;
            float w1 = l1 ? __int_as_float(p1.y) : 0.0f;
            ax += w0 * __uint_as_float(g0.x << 16);
            ay += w0 * __uint_as_float(g0.x & 0xFFFF0000u);
            az += w0 * __uint_as_float(g0.y << 16);
            aw += w0 * __uint_as_float(g0.y & 0xFFFF0000u);
            ax += w1 * __uint_as_float(g1.x << 16);
            ay += w1 * __uint_as_float(g1.x & 0xFFFF0000u);
            az += w1 * __uint_as_float(g1.y << 16);
            aw += w1 * __uint_as_float(g1.y & 0xFFFF0000u);
        }
    }

    ax += __shfl_xor(ax, 16); ay += __shfl_xor(ay, 16);
    az += __shfl_xor(az, 16); aw += __shfl_xor(aw, 16);
    ax += __shfl_xor(ax, 32); ay += __shfl_xor(ay, 32);
    az += __shfl_xor(az, 32); aw += __shfl_xor(aw, 32);

    if (grp == 0) {
        const float4 hv = *(const float4*)(h + (size_t)node * HID + sub * 4);
        float4 o;
        o.x = hv.x + ax; o.y = hv.y + ay; o.z = hv.z + az; o.w = hv.w + aw;
        *(float4*)(a + (size_t)node * HID + sub * 4) = o;
    }
}

extern "C" void kernel_launch(void* const* d_in, const int* in_sizes, int n_in,
                              void* d_out, int out_size, void* d_ws, size_t ws_size,
                              hipStream_t stream) {
    const float* x   = (const float*)d_in[0];
    const int*   ei  = (const int*)  d_in[1];   // (2, E): [src | tgt]
    const float* ea  = (const float*)d_in[2];
    const float* Wi  = (const float*)d_in[3];
    const float* bi  = (const float*)d_in[4];
    const float* W1  = (const float*)d_in[5];
    const float* b1  = (const float*)d_in[6];
    const float* W2  = (const float*)d_in[7];
    const float* b2  = (const float*)d_in[8];
    const float* W3  = (const float*)d_in[9];
    const float* b3  = (const float*)d_in[10];
    const float* bl[3] = { b1, b2, b3 };
    float* out = (float*)d_out;  // (4, N, HID)

    const int* src = ei;
    const int* tgt = ei + N_EDGES;

    // Workspace layout. binned (CSR-build phase) overlaps tmp (layer phase).
    float* tmp  = (float*)d_ws;                           // N*HID f32 (25.6 MB)
    unsigned long long* binned = (unsigned long long*)d_ws;
    int* offs         = (int*)(tmp + (size_t)N_NODES * HID);
    int* counts       = offs + N_NODES;
    int* g_bin_cnt    = counts + N_NODES;
    int* g_bin_offs   = g_bin_cnt + NBINS;
    int* g_bin_cursor = g_bin_offs + NBINS;
    int* endi         = g_bin_cursor + NBINS;
    unsigned long long* pairs = (unsigned long long*)(endi + 1);   // 8B-aligned
    __hip_bfloat16* hbf = (__hip_bfloat16*)(pairs + N_EDGES);      // N*HID bf16
    unsigned short* wf_in  = (unsigned short*)(hbf + (size_t)N_NODES * HID);
    unsigned short* wf_hid = wf_in + 8192;                          // 3 x 4096

    hipMemsetAsync(g_bin_cnt, 0, NBINS * sizeof(int), stream);

    wf_prep_kernel<<<32, 256, 0, stream>>>(Wi, W1, W2, W3, wf_in, wf_hid);

    const int eb_blocks = (N_EDGES + EB - 1) / EB;  // 782
    bin_hist_kernel   <<<eb_blocks, 256, 0, stream>>>(tgt, g_bin_cnt);
    bin_scan_kernel   <<<1, 512, 0, stream>>>(g_bin_cnt, g_bin_offs, g_bin_cursor);
    bin_scatter_kernel<<<eb_blocks, 256, 0, stream>>>(src, tgt, ea, g_bin_cursor, binned);
    fine_fill_kernel  <<<NBINS, 256, 0, stream>>>(binned, g_bin_offs, g_bin_cnt,
                                                  offs, counts, pairs);

    const int gemm_blocks = (N_NODES + 63) / 64;  // 1563
    gemm_in_kernel<<<gemm_blocks, 256, 0, stream>>>(x, wf_in, bi, out, hbf);

    for (int l = 0; l < 3; ++l) {
        const float* h = out + (size_t)l * N_NODES * HID;
        float* hn      = out + (size_t)(l + 1) * N_NODES * HID;
        aggregate_kernel<<<(N_NODES + 3) / 4, 256, 0, stream>>>(
            h, hbf, offs, counts, (const int2*)pairs, tmp);
        gemm_hid_kernel<<<gemm_blocks, 256, 0, stream>>>(
            tmp, wf_hid + (size_t)l * 4096, bl[l], hn, hbf);
    }
}